// Round 2
// baseline (696.060 us; speedup 1.0000x reference)
//
#include <hip/hip_runtime.h>
#include <hip/hip_bf16.h>

// Mixtral sparse MoE: T=4096 tokens, D=1024, F=3584, E=8, top-2.
// Pipeline: route -> scan -> scatter -> cvt(x) -> cvt(w1|w3 interleaved)
//   -> GEMM1 (m97-style gload_lds, fused silu*mul -> h bf16)
//   -> cvt(w2) [reuses w13 space] -> GEMM2 (-> res bf16, no atomics)
//   -> combine (out[t] = wA*res[posA] + wB*res[posB])

#define T_TOK 4096
#define DIM   1024
#define FF    3584
#define NE    8
#define BM    128
#define CAP   (T_TOK*2 + NE*BM)   // 9216 padded pair rows

// ws byte offsets
#define OFF_TOPI   256UL
#define OFF_TOPW   33024UL
#define OFF_TOKPOS 65792UL
#define OFF_ROWTOK 98560UL
#define OFF_XB     135424UL
#define OFF_BIG    8524032UL                 // OFF_XB + T*D*2
#define OFF_W2B    OFF_BIG                   // 58,720,256 B (after gemm1)
#define OFF_RES    (OFF_BIG + 58720256UL)    // CAP*D*2 = 18,874,368 B
#define OFF_H      (OFF_BIG + 117440512UL)   // CAP*F*2 = 66,060,288 B
#define WS_NEED    (OFF_H + 66060288UL)      // 192,024,832 B

using f32x4 = __attribute__((ext_vector_type(4))) float;
using s16x8 = __attribute__((ext_vector_type(8))) short;

__device__ __forceinline__ ushort f2b(float f) {
    __hip_bfloat16 b = __float2bfloat16(f);   // RNE
    ushort u; __builtin_memcpy(&u, &b, 2); return u;
}
__device__ __forceinline__ float blo(uint u){ u <<= 16; float f; __builtin_memcpy(&f,&u,4); return f; }
__device__ __forceinline__ float bhi(uint u){ u &= 0xFFFF0000u; float f; __builtin_memcpy(&f,&u,4); return f; }

__device__ __forceinline__ void gl_lds16(const ushort* g, ushort* l) {
    __builtin_amdgcn_global_load_lds(
        (const __attribute__((address_space(1))) void*)g,
        (__attribute__((address_space(3))) void*)l, 16, 0, 0);
}

__device__ __forceinline__ uint4 pack8(float4 v0, float4 v1) {
    uint4 o;
    o.x = f2b(v0.x) | ((uint)f2b(v0.y) << 16);
    o.y = f2b(v0.z) | ((uint)f2b(v0.w) << 16);
    o.z = f2b(v1.x) | ((uint)f2b(v1.y) << 16);
    o.w = f2b(v1.z) | ((uint)f2b(v1.w) << 16);
    return o;
}

// ---------------- routing: one wave per token ----------------
__global__ __launch_bounds__(256)
void k_route(const float* __restrict__ x, const float* __restrict__ gw,
             int* __restrict__ topi, float* __restrict__ topw, int* __restrict__ counts)
{
    __shared__ float gws[NE*DIM];                       // 32 KB
    const int tid = threadIdx.x;
    for (int i = tid; i < NE*DIM/4; i += 256)
        ((float4*)gws)[i] = ((const float4*)gw)[i];
    __syncthreads();

    const int lane = tid & 63, wid = tid >> 6;
    const int t = blockIdx.x*4 + wid;

    float4 xr[4];
    const float4* xrow = (const float4*)(x + (size_t)t*DIM) + lane*4;
    #pragma unroll
    for (int i = 0; i < 4; ++i) xr[i] = xrow[i];

    float lg[NE];
    #pragma unroll
    for (int e = 0; e < NE; ++e) {
        const float4* g4 = (const float4*)(gws + e*DIM) + lane*4;
        float s = 0.f;
        #pragma unroll
        for (int i = 0; i < 4; ++i) {
            float4 g = g4[i];
            s += xr[i].x*g.x + xr[i].y*g.y + xr[i].z*g.z + xr[i].w*g.w;
        }
        #pragma unroll
        for (int off = 32; off; off >>= 1) s += __shfl_xor(s, off);
        lg[e] = s;
    }
    if (lane == 0) {
        float b1 = -1e30f, b2 = -1e30f; int i1 = 0, i2 = 0;
        #pragma unroll
        for (int e = 0; e < NE; ++e) {
            float v = lg[e];
            if (v > b1)      { b2 = b1; i2 = i1; b1 = v; i1 = e; }
            else if (v > b2) { b2 = v; i2 = e; }
        }
        float p2 = __expf(b2 - b1);     // softmax denom cancels in top-k renorm
        float inv = 1.f / (1.f + p2);
        topi[2*t]   = i1; topi[2*t+1] = i2;
        topw[2*t]   = inv; topw[2*t+1] = p2*inv;
        atomicAdd(&counts[i1], 1); atomicAdd(&counts[i2], 1);
    }
}

// ---------------- scan: padded per-expert offsets + rowTok=-1 ----------------
__global__ void k_scan(const int* __restrict__ counts, int* __restrict__ offs,
                       int* __restrict__ rowTok)
{
    if (threadIdx.x == 0) {
        int acc = 0; offs[0] = 0;
        for (int e = 0; e < NE; ++e) {
            int p = (counts[e] + BM - 1) & ~(BM - 1);
            acc += p; offs[e+1] = acc;
        }
    }
    for (int i = threadIdx.x; i < CAP; i += blockDim.x) rowTok[i] = -1;
}

// ---------------- scatter tokens into per-expert row lists ----------------
__global__ __launch_bounds__(256)
void k_scatter(const int* __restrict__ topi,
               const int* __restrict__ offs, int* __restrict__ cursor,
               int* __restrict__ rowTok, int* __restrict__ tokPos)
{
    int t = blockIdx.x*256 + threadIdx.x;
    #pragma unroll
    for (int j = 0; j < 2; ++j) {
        int e = topi[2*t + j];
        int pos = offs[e] + atomicAdd(&cursor[e], 1);
        rowTok[pos] = t;
        tokPos[2*t + j] = pos;
    }
}

// ---------------- fp32 -> bf16 straight ----------------
__global__ __launch_bounds__(256)
void k_cvt(const float* __restrict__ src, ushort* __restrict__ dst)
{
    size_t i = (size_t)blockIdx.x*256 + threadIdx.x;    // 8 elems each
    float4 v0 = ((const float4*)src)[2*i], v1 = ((const float4*)src)[2*i+1];
    ((uint4*)dst)[i] = pack8(v0, v1);
}

// ---------------- w1|w3 -> interleaved bf16 [e][c<56][s<2][r<64][k<1024] -----
__global__ __launch_bounds__(256)
void k_cvt13(const float* __restrict__ w1, const float* __restrict__ w3,
             ushort* __restrict__ w13)
{
    int i = blockIdx.x*256 + threadIdx.x;    // 8-elem group along k
    int k8 = i & 127;
    int rd = i >> 7;                          // dst row, 0..57343
    int e   = rd / 7168;
    int rem = rd - e*7168;
    int c   = rem >> 7;
    int rem2= rem & 127;
    int s   = rem2 >> 6;
    int r   = rem2 & 63;
    const float* src = (s ? w3 : w1) + ((size_t)e*FF + c*64 + r)*DIM + k8*8;
    float4 v0 = ((const float4*)src)[0], v1 = ((const float4*)src)[1];
    ((uint4*)w13)[i] = pack8(v0, v1);
}

// ---------------- GEMM1: h = silu(xg @ w1^T) * (xg @ w3^T) ----------------
// m97 structure: 128 padded rows x 64 f-cols, BK=64, gload_lds staging,
// linear LDS, double-buffered, 2 barriers per K-tile.
__global__ __launch_bounds__(256, 2)
void k_gemm1(const ushort* __restrict__ xb, const ushort* __restrict__ w13,
             const int* __restrict__ offs, const int* __restrict__ rowTok,
             ushort* __restrict__ hout)
{
    __shared__ __align__(16) ushort As[2][128*64];   // 16 KB each
    __shared__ __align__(16) ushort Bs[2][128*64];
    const int rowStart = blockIdx.y * BM;
    if (rowStart >= offs[8]) return;
    int e = 0;
    #pragma unroll
    for (int k = 1; k < NE; ++k) if (rowStart >= offs[k]) e = k;

    const int fc2 = blockIdx.x;                       // 0..55
    const ushort* Wb = w13 + ((size_t)(e*56 + fc2) * 128) * DIM;

    const int tid = threadIdx.x;
    const int lane = tid & 63, wid = tid >> 6;
    const int wr = wid >> 1, wc = wid & 1;
    const int lo = lane & 15, hi = lane >> 4;
    const int lr = lane >> 3;     // row within 8-row chunk
    const int lc = lane & 7;      // 16B col chunk

    const ushort* aSrc[4];
    const ushort* bSrc[4];
    #pragma unroll
    for (int i = 0; i < 4; ++i) {
        int row = wid*32 + i*8 + lr;
        int tok = rowTok[rowStart + row]; if (tok < 0) tok = 0;   // pad -> finite garbage
        aSrc[i] = xb + (size_t)tok*DIM + lc*8;
        bSrc[i] = Wb + (size_t)row*DIM + lc*8;
    }

    auto stage = [&](int buf, int kt) {
        ushort* Ab = &As[buf][0] + wid*4*512;
        ushort* Bb = &Bs[buf][0] + wid*4*512;
        #pragma unroll
        for (int i = 0; i < 4; ++i) {
            gl_lds16(aSrc[i] + kt*64, Ab + i*512);
            gl_lds16(bSrc[i] + kt*64, Bb + i*512);
        }
    };

    f32x4 acc1[4][2], acc3[4][2];
    #pragma unroll
    for (int m = 0; m < 4; ++m)
        #pragma unroll
        for (int n = 0; n < 2; ++n) { acc1[m][n] = (f32x4)(0.f); acc3[m][n] = (f32x4)(0.f); }

    auto compute = [&](int buf) {
        const ushort* Ab = &As[buf][0];
        const ushort* Bb = &Bs[buf][0];
        #pragma unroll
        for (int kk = 0; kk < 2; ++kk) {
            s16x8 a[4], b1[2], b3[2];
            #pragma unroll
            for (int m = 0; m < 4; ++m)
                a[m] = *(const s16x8*)(Ab + (wr*64 + m*16 + lo)*64 + kk*32 + hi*8);
            #pragma unroll
            for (int n = 0; n < 2; ++n) {
                b1[n] = *(const s16x8*)(Bb + (wc*32 + n*16 + lo)*64 + kk*32 + hi*8);
                b3[n] = *(const s16x8*)(Bb + (64 + wc*32 + n*16 + lo)*64 + kk*32 + hi*8);
            }
            #pragma unroll
            for (int m = 0; m < 4; ++m)
                #pragma unroll
                for (int n = 0; n < 2; ++n) {
                    acc1[m][n] = __builtin_amdgcn_mfma_f32_16x16x32_bf16(a[m], b1[n], acc1[m][n], 0, 0, 0);
                    acc3[m][n] = __builtin_amdgcn_mfma_f32_16x16x32_bf16(a[m], b3[n], acc3[m][n], 0, 0, 0);
                }
        }
    };

    stage(0, 0);
    __syncthreads();
    int cur = 0;
    const int NK = DIM/64;   // 16
    for (int kt = 0; kt < NK; ++kt) {
        if (kt + 1 < NK) stage(cur ^ 1, kt + 1);
        compute(cur);
        __syncthreads();
        cur ^= 1;
    }

    const int fc = fc2 * 64;
    #pragma unroll
    for (int m = 0; m < 4; ++m)
        #pragma unroll
        for (int n = 0; n < 2; ++n) {
            f32x4 v1 = acc1[m][n], v3 = acc3[m][n];
            int col = fc + wc*32 + n*16 + lo;
            #pragma unroll
            for (int j = 0; j < 4; ++j) {
                int row = wr*64 + m*16 + hi*4 + j;
                float s = v1[j];
                float val = (s / (1.f + __expf(-s))) * v3[j];
                hout[(size_t)(rowStart + row)*FF + col] = f2b(val);
            }
        }
}

// ---------------- GEMM2: res = h @ w2^T (bf16 per padded row) ----------------
__global__ __launch_bounds__(256, 2)
void k_gemm2(const ushort* __restrict__ h, const ushort* __restrict__ w2b,
             const int* __restrict__ offs, ushort* __restrict__ res)
{
    __shared__ __align__(16) ushort As[2][128*64];
    __shared__ __align__(16) ushort Bs[2][128*64];
    const int rowStart = blockIdx.y * BM;
    if (rowStart >= offs[8]) return;
    int e = 0;
    #pragma unroll
    for (int k = 1; k < NE; ++k) if (rowStart >= offs[k]) e = k;

    const int dc = blockIdx.x * 128;
    const ushort* Wb = w2b + ((size_t)e*DIM + dc)*FF;

    const int tid = threadIdx.x;
    const int lane = tid & 63, wid = tid >> 6;
    const int wr = wid >> 1, wc = wid & 1;
    const int lo = lane & 15, hi = lane >> 4;
    const int lr = lane >> 3;
    const int lc = lane & 7;

    const ushort* aSrc[4];
    const ushort* bSrc[4];
    #pragma unroll
    for (int i = 0; i < 4; ++i) {
        int row = wid*32 + i*8 + lr;
        aSrc[i] = h  + (size_t)(rowStart + row)*FF + lc*8;
        bSrc[i] = Wb + (size_t)row*FF + lc*8;
    }

    auto stage = [&](int buf, int kt) {
        ushort* Ab = &As[buf][0] + wid*4*512;
        ushort* Bb = &Bs[buf][0] + wid*4*512;
        #pragma unroll
        for (int i = 0; i < 4; ++i) {
            gl_lds16(aSrc[i] + kt*64, Ab + i*512);
            gl_lds16(bSrc[i] + kt*64, Bb + i*512);
        }
    };

    f32x4 acc[4][4];
    #pragma unroll
    for (int m = 0; m < 4; ++m)
        #pragma unroll
        for (int n = 0; n < 4; ++n) acc[m][n] = (f32x4)(0.f);

    auto compute = [&](int buf) {
        const ushort* Ab = &As[buf][0];
        const ushort* Bb = &Bs[buf][0];
        #pragma unroll
        for (int kk = 0; kk < 2; ++kk) {
            s16x8 a[4], b[4];
            #pragma unroll
            for (int m = 0; m < 4; ++m)
                a[m] = *(const s16x8*)(Ab + (wr*64 + m*16 + lo)*64 + kk*32 + hi*8);
            #pragma unroll
            for (int n = 0; n < 4; ++n)
                b[n] = *(const s16x8*)(Bb + (wc*64 + n*16 + lo)*64 + kk*32 + hi*8);
            #pragma unroll
            for (int m = 0; m < 4; ++m)
                #pragma unroll
                for (int n = 0; n < 4; ++n)
                    acc[m][n] = __builtin_amdgcn_mfma_f32_16x16x32_bf16(a[m], b[n], acc[m][n], 0, 0, 0);
        }
    };

    stage(0, 0);
    __syncthreads();
    int cur = 0;
    const int NK = FF/64;   // 56
    for (int kt = 0; kt < NK; ++kt) {
        if (kt + 1 < NK) stage(cur ^ 1, kt + 1);
        compute(cur);
        __syncthreads();
        cur ^= 1;
    }

    #pragma unroll
    for (int m = 0; m < 4; ++m)
        #pragma unroll
        for (int j = 0; j < 4; ++j) {
            int prow = rowStart + wr*64 + m*16 + hi*4 + j;
            #pragma unroll
            for (int n = 0; n < 4; ++n) {
                int d = dc + wc*64 + n*16 + lo;
                res[(size_t)prow*DIM + d] = f2b(acc[m][n][j]);
            }
        }
}

// ---------------- combine: out[t] = wA*res[posA] + wB*res[posB] --------------
__global__ __launch_bounds__(256)
void k_combine(const ushort* __restrict__ res, const int* __restrict__ tokPos,
               const float* __restrict__ topw, float* __restrict__ out)
{
    int i = blockIdx.x*256 + threadIdx.x;    // 8-elem group
    int t = i >> 7;                           // D/8 = 128 groups per token
    int g = i & 127;
    int pA = tokPos[2*t], pB = tokPos[2*t+1];
    float wA = topw[2*t], wB = topw[2*t+1];
    uint4 a = *(const uint4*)(res + (size_t)pA*DIM + g*8);
    uint4 b = *(const uint4*)(res + (size_t)pB*DIM + g*8);
    float4 o0, o1;
    o0.x = wA*blo(a.x) + wB*blo(b.x);  o0.y = wA*bhi(a.x) + wB*bhi(b.x);
    o0.z = wA*blo(a.y) + wB*blo(b.y);  o0.w = wA*bhi(a.y) + wB*bhi(b.y);
    o1.x = wA*blo(a.z) + wB*blo(b.z);  o1.y = wA*bhi(a.z) + wB*bhi(b.z);
    o1.z = wA*blo(a.w) + wB*blo(b.w);  o1.w = wA*bhi(a.w) + wB*bhi(b.w);
    float4* dst = (float4*)(out + (size_t)t*DIM + g*8);
    dst[0] = o0; dst[1] = o1;
}

// ---------------- launch ----------------
extern "C" void kernel_launch(void* const* d_in, const int* in_sizes, int n_in,
                              void* d_out, int out_size, void* d_ws, size_t ws_size,
                              hipStream_t stream)
{
    const float* x  = (const float*)d_in[0];
    const float* gw = (const float*)d_in[1];
    const float* w1 = (const float*)d_in[2];
    const float* w3 = (const float*)d_in[3];
    const float* w2 = (const float*)d_in[4];
    float* out = (float*)d_out;
    char* ws = (char*)d_ws;
    if (ws_size < WS_NEED) return;   // fail loudly (out stays poisoned)

    int*    counts = (int*)ws;                    // 8
    int*    cursor = counts + 8;                  // 8
    int*    offs   = counts + 16;                 // 9
    int*    topi   = (int*)  (ws + OFF_TOPI);
    float*  topw   = (float*)(ws + OFF_TOPW);
    int*    tokPos = (int*)  (ws + OFF_TOKPOS);
    int*    rowTok = (int*)  (ws + OFF_ROWTOK);
    ushort* xb     = (ushort*)(ws + OFF_XB);
    ushort* w13b   = (ushort*)(ws + OFF_BIG);
    ushort* w2b    = (ushort*)(ws + OFF_W2B);
    ushort* res    = (ushort*)(ws + OFF_RES);
    ushort* h      = (ushort*)(ws + OFF_H);

    hipMemsetAsync(ws, 0, 256, stream);   // counts + cursor

    k_route  <<<T_TOK/4, 256, 0, stream>>>(x, gw, topi, topw, counts);
    k_scan   <<<1, 256, 0, stream>>>(counts, offs, rowTok);
    k_scatter<<<T_TOK/256, 256, 0, stream>>>(topi, offs, cursor, rowTok, tokPos);
    k_cvt    <<<(T_TOK*DIM/8)/256, 256, 0, stream>>>(x, xb);
    k_cvt13  <<<(2*NE*FF*DIM/8)/256, 256, 0, stream>>>(w1, w3, w13b);
    k_gemm1  <<<dim3(FF/64,  CAP/BM), 256, 0, stream>>>(xb, w13b, offs, rowTok, h);
    k_cvt    <<<(NE*DIM*FF/8)/256, 256, 0, stream>>>(w2, w2b);   // overwrites w13b
    k_gemm2  <<<dim3(DIM/128, CAP/BM), 256, 0, stream>>>(h, w2b, offs, res);
    k_combine<<<(T_TOK*DIM/8)/256, 256, 0, stream>>>(res, tokPos, topw, out);
}

// Round 3
// 539.518 us; speedup vs baseline: 1.2902x; 1.2902x over previous
//
#include <hip/hip_runtime.h>
#include <hip/hip_bf16.h>

// Mixtral sparse MoE: T=4096 tokens, D=1024, F=3584, E=8, top-2.
// route -> scan -> scatter -> cvt(x) -> cvt13 -> GEMM1(8-phase-style, silu*mul)
//   -> cvt(w2) -> GEMM2 -> combine

#define T_TOK 4096
#define DIM   1024
#define FF    3584
#define NE    8
#define BM    128
#define CAP   (T_TOK*2 + NE*BM)   // 9216 padded pair rows

// ws byte offsets (identical budget to round 2: 192,024,832 B)
#define OFF_TOPI   256UL
#define OFF_TOPW   33024UL
#define OFF_TOKPOS 65792UL
#define OFF_ROWTOK 98560UL
#define OFF_XB     135424UL
#define OFF_BIG    8524032UL
#define OFF_W2B    OFF_BIG
#define OFF_RES    (OFF_BIG + 58720256UL)
#define OFF_H      (OFF_BIG + 117440512UL)
#define WS_NEED    (OFF_H + 66060288UL)

using f32x4 = __attribute__((ext_vector_type(4))) float;
using s16x8 = __attribute__((ext_vector_type(8))) short;

__device__ __forceinline__ ushort f2b(float f) {
    __hip_bfloat16 b = __float2bfloat16(f);
    ushort u; __builtin_memcpy(&u, &b, 2); return u;
}
__device__ __forceinline__ float blo(uint u){ u <<= 16; float f; __builtin_memcpy(&f,&u,4); return f; }
__device__ __forceinline__ float bhi(uint u){ u &= 0xFFFF0000u; float f; __builtin_memcpy(&f,&u,4); return f; }

__device__ __forceinline__ void gl_lds16(const ushort* g, ushort* l) {
    __builtin_amdgcn_global_load_lds(
        (const __attribute__((address_space(1))) void*)g,
        (__attribute__((address_space(3))) void*)l, 16, 0, 0);
}
__device__ __forceinline__ uint4 pack8(float4 v0, float4 v1) {
    uint4 o;
    o.x = f2b(v0.x) | ((uint)f2b(v0.y) << 16);
    o.y = f2b(v0.z) | ((uint)f2b(v0.w) << 16);
    o.z = f2b(v1.x) | ((uint)f2b(v1.y) << 16);
    o.w = f2b(v1.z) | ((uint)f2b(v1.w) << 16);
    return o;
}

#define LGKM0 do { asm volatile("s_waitcnt lgkmcnt(0)" ::: "memory"); \
                   __builtin_amdgcn_sched_barrier(0); } while (0)
#define VMC(n) asm volatile("s_waitcnt vmcnt(" #n ")" ::: "memory")
#define BAR()  __builtin_amdgcn_s_barrier()

// ---------------- routing: one wave per token ----------------
__global__ __launch_bounds__(256)
void k_route(const float* __restrict__ x, const float* __restrict__ gw,
             int* __restrict__ topi, float* __restrict__ topw, int* __restrict__ counts)
{
    __shared__ float gws[NE*DIM];
    const int tid = threadIdx.x;
    for (int i = tid; i < NE*DIM/4; i += 256)
        ((float4*)gws)[i] = ((const float4*)gw)[i];
    __syncthreads();

    const int lane = tid & 63, wid = tid >> 6;
    const int t = blockIdx.x*4 + wid;

    float4 xr[4];
    const float4* xrow = (const float4*)(x + (size_t)t*DIM) + lane*4;
    #pragma unroll
    for (int i = 0; i < 4; ++i) xr[i] = xrow[i];

    float lg[NE];
    #pragma unroll
    for (int e = 0; e < NE; ++e) {
        const float4* g4 = (const float4*)(gws + e*DIM) + lane*4;
        float s = 0.f;
        #pragma unroll
        for (int i = 0; i < 4; ++i) {
            float4 g = g4[i];
            s += xr[i].x*g.x + xr[i].y*g.y + xr[i].z*g.z + xr[i].w*g.w;
        }
        #pragma unroll
        for (int off = 32; off; off >>= 1) s += __shfl_xor(s, off);
        lg[e] = s;
    }
    if (lane == 0) {
        float b1 = -1e30f, b2 = -1e30f; int i1 = 0, i2 = 0;
        #pragma unroll
        for (int e = 0; e < NE; ++e) {
            float v = lg[e];
            if (v > b1)      { b2 = b1; i2 = i1; b1 = v; i1 = e; }
            else if (v > b2) { b2 = v; i2 = e; }
        }
        float p2 = __expf(b2 - b1);
        float inv = 1.f / (1.f + p2);
        topi[2*t]   = i1; topi[2*t+1] = i2;
        topw[2*t]   = inv; topw[2*t+1] = p2*inv;
        atomicAdd(&counts[i1], 1); atomicAdd(&counts[i2], 1);
    }
}

__global__ void k_scan(const int* __restrict__ counts, int* __restrict__ offs,
                       int* __restrict__ rowTok)
{
    if (threadIdx.x == 0) {
        int acc = 0; offs[0] = 0;
        for (int e = 0; e < NE; ++e) {
            int p = (counts[e] + BM - 1) & ~(BM - 1);
            acc += p; offs[e+1] = acc;
        }
    }
    for (int i = threadIdx.x; i < CAP; i += blockDim.x) rowTok[i] = -1;
}

__global__ __launch_bounds__(256)
void k_scatter(const int* __restrict__ topi,
               const int* __restrict__ offs, int* __restrict__ cursor,
               int* __restrict__ rowTok, int* __restrict__ tokPos)
{
    int t = blockIdx.x*256 + threadIdx.x;
    #pragma unroll
    for (int j = 0; j < 2; ++j) {
        int e = topi[2*t + j];
        int pos = offs[e] + atomicAdd(&cursor[e], 1);
        rowTok[pos] = t;
        tokPos[2*t + j] = pos;
    }
}

__global__ __launch_bounds__(256)
void k_cvt(const float* __restrict__ src, ushort* __restrict__ dst)
{
    size_t i = (size_t)blockIdx.x*256 + threadIdx.x;
    float4 v0 = ((const float4*)src)[2*i], v1 = ((const float4*)src)[2*i+1];
    ((uint4*)dst)[i] = pack8(v0, v1);
}

// w13 layout: [e][pb 14][sc 512][k 1024]; sc = g*64 + half*32 + c, f = pb*256+g*32+c
__global__ __launch_bounds__(256)
void k_cvt13(const float* __restrict__ w1, const float* __restrict__ w3,
             ushort* __restrict__ w13)
{
    int i = blockIdx.x*256 + threadIdx.x;
    int k8 = i & 127;
    int rd = i >> 7;
    int e   = rd / 7168;
    int rem = rd - e*7168;
    int pb  = rem >> 9;
    int sc  = rem & 511;
    int g = sc >> 6, half = (sc >> 5) & 1, c = sc & 31;
    int f = pb*256 + g*32 + c;
    const float* src = (half ? w3 : w1) + ((size_t)e*FF + f)*DIM + k8*8;
    float4 v0 = ((const float4*)src)[0], v1 = ((const float4*)src)[1];
    ((uint4*)w13)[i] = pack8(v0, v1);
}

// ---------------- GEMM1: 128 rows x 512 stacked-cols, BK=32 ----------------
// 8 waves, each 128x64; 3-buffer LDS ring; counted vmcnt(5); swizzled src+read.
__global__ __launch_bounds__(512)
void k_gemm1(const ushort* __restrict__ xb, const ushort* __restrict__ w13,
             const int* __restrict__ offs, const int* __restrict__ rowTok,
             ushort* __restrict__ hout)
{
    __shared__ __align__(16) ushort As[3][128*32];   // 24 KB
    __shared__ __align__(16) ushort Bs[3][512*32];   // 96 KB
    const int rowStart = blockIdx.y * BM;
    if (rowStart >= offs[8]) return;
    int e = 0;
    #pragma unroll
    for (int k = 1; k < NE; ++k) if (rowStart >= offs[k]) e = k;
    const int pb = blockIdx.x;   // 0..13
    const ushort* __restrict__ Wb = w13 + ((size_t)(e*14 + pb)) * 512 * DIM;

    const int tid = threadIdx.x;
    const int lane = tid & 63, wid = tid >> 6;   // wid = n-wave 0..7
    const int lo = lane & 15, hi = lane >> 4;

    // staging: thread -> row tid>>2, chunk tid&3 (pre-swizzled source)
    const int srow = tid >> 2;
    const int q    = tid & 3;
    const int sig  = (tid >> 3) & 3;             // (srow>>1)&3
    int tokS = rowTok[rowStart + srow]; if (tokS < 0) tokS = 0;
    const ushort* aS = xb + (size_t)tokS*DIM + (q ^ sig)*8;
    const ushort* bS = Wb + (size_t)srow*DIM + (q ^ sig)*8;

    // read offsets (swizzled)
    const int sig2  = (lo >> 1) & 3;
    const int rdA   = lo*32 + ((hi ^ sig2) * 8);
    const int rdB   = (wid*64 + lo)*32 + ((hi ^ sig2) * 8);

    f32x4 acc[8][4];
    #pragma unroll
    for (int m = 0; m < 8; ++m)
        #pragma unroll
        for (int n = 0; n < 4; ++n) acc[m][n] = (f32x4)(0.f);

    // prologue: stage tiles 0,1
    #pragma unroll
    for (int t0 = 0; t0 < 2; ++t0) {
        gl_lds16(aS + t0*32, &As[t0][0] + wid*512);
        #pragma unroll
        for (int j = 0; j < 4; ++j)
            gl_lds16(bS + (size_t)j*(128*DIM) + t0*32, &Bs[t0][0] + j*4096 + wid*512);
    }
    VMC(5);
    BAR();

    int cur = 0, nxt = 2;
    const int NK = DIM/32;   // 32
    for (int t = 0; t < NK; ++t) {
        const ushort* Ab = &As[cur][0];
        const ushort* Bb = &Bs[cur][0];
        const bool pf = (t + 2 < NK);
        s16x8 a[4], b[4];
        // ---- phase 0: m-half 0 ----
        #pragma unroll
        for (int n = 0; n < 4; ++n) b[n] = *(const s16x8*)(Bb + n*512 + rdB);
        #pragma unroll
        for (int m = 0; m < 4; ++m) a[m] = *(const s16x8*)(Ab + m*512 + rdA);
        if (pf) {
            gl_lds16(aS + (t+2)*32, &As[nxt][0] + wid*512);
            gl_lds16(bS + (t+2)*32,                 &Bs[nxt][0] + wid*512);
            gl_lds16(bS + (size_t)(128*DIM) + (t+2)*32, &Bs[nxt][0] + 4096 + wid*512);
        }
        BAR();
        LGKM0;
        __builtin_amdgcn_s_setprio(1);
        #pragma unroll
        for (int m = 0; m < 4; ++m)
            #pragma unroll
            for (int n = 0; n < 4; ++n)
                acc[m][n] = __builtin_amdgcn_mfma_f32_16x16x32_bf16(a[m], b[n], acc[m][n], 0, 0, 0);
        __builtin_amdgcn_s_setprio(0);
        BAR();
        // ---- phase 1: m-half 1 ----
        #pragma unroll
        for (int m = 0; m < 4; ++m) a[m] = *(const s16x8*)(Ab + 2048 + m*512 + rdA);
        if (pf) {
            gl_lds16(bS + (size_t)(256*DIM) + (t+2)*32, &Bs[nxt][0] + 8192  + wid*512);
            gl_lds16(bS + (size_t)(384*DIM) + (t+2)*32, &Bs[nxt][0] + 12288 + wid*512);
        }
        BAR();
        LGKM0;
        __builtin_amdgcn_s_setprio(1);
        #pragma unroll
        for (int m = 0; m < 4; ++m)
            #pragma unroll
            for (int n = 0; n < 4; ++n)
                acc[4+m][n] = __builtin_amdgcn_mfma_f32_16x16x32_bf16(a[m], b[n], acc[4+m][n], 0, 0, 0);
        __builtin_amdgcn_s_setprio(0);
        if (t == NK-2) { VMC(0); } else { VMC(5); }
        BAR();
        cur = (cur == 2) ? 0 : cur + 1;
        nxt = (nxt == 2) ? 0 : nxt + 1;
    }

    // epilogue: silu(w1-part)*w3-part -> h
    const int fbase = pb*256 + wid*32;
    #pragma unroll
    for (int m = 0; m < 8; ++m)
        #pragma unroll
        for (int n = 0; n < 2; ++n) {
            f32x4 v1 = acc[m][n], v3 = acc[m][n+2];
            int f = fbase + n*16 + lo;
            #pragma unroll
            for (int j = 0; j < 4; ++j) {
                int row = m*16 + hi*4 + j;
                float s = v1[j];
                float val = (s / (1.f + __expf(-s))) * v3[j];
                hout[(size_t)(rowStart + row)*FF + f] = f2b(val);
            }
        }
}

// ---------------- GEMM2: 128 rows x 256 d-cols, BK=32 ----------------
// 8 waves (2Mx4N), each 64x64; 3-buffer ring; vmcnt(3); swizzled.
__global__ __launch_bounds__(512)
void k_gemm2(const ushort* __restrict__ h, const ushort* __restrict__ w2b,
             const int* __restrict__ offs, ushort* __restrict__ res)
{
    __shared__ __align__(16) ushort As[3][128*32];   // 24 KB
    __shared__ __align__(16) ushort Bs[3][256*32];   // 48 KB
    const int rowStart = blockIdx.y * BM;
    if (rowStart >= offs[8]) return;
    int e = 0;
    #pragma unroll
    for (int k = 1; k < NE; ++k) if (rowStart >= offs[k]) e = k;
    const int dc = blockIdx.x * 256;
    const ushort* __restrict__ W2 = w2b + ((size_t)e*DIM + dc)*FF;

    const int tid = threadIdx.x;
    const int lane = tid & 63, wid = tid >> 6;
    const int wr = wid >> 2, wc = wid & 3;
    const int lo = lane & 15, hi = lane >> 4;

    const int srow = tid >> 2;
    const int q    = tid & 3;
    const int sig  = (tid >> 3) & 3;
    const ushort* aS = h  + (size_t)(rowStart + srow)*FF + (q ^ sig)*8;
    const ushort* bS = W2 + (size_t)srow*FF + (q ^ sig)*8;

    const int sig2 = (lo >> 1) & 3;
    const int rdA  = (wr*64 + lo)*32 + ((hi ^ sig2) * 8);
    const int rdB  = (wc*64 + lo)*32 + ((hi ^ sig2) * 8);

    f32x4 acc[4][4];
    #pragma unroll
    for (int m = 0; m < 4; ++m)
        #pragma unroll
        for (int n = 0; n < 4; ++n) acc[m][n] = (f32x4)(0.f);

    #pragma unroll
    for (int t0 = 0; t0 < 2; ++t0) {
        gl_lds16(aS + t0*32, &As[t0][0] + wid*512);
        #pragma unroll
        for (int j = 0; j < 2; ++j)
            gl_lds16(bS + (size_t)j*(128*FF) + t0*32, &Bs[t0][0] + j*4096 + wid*512);
    }
    VMC(3);
    BAR();

    int cur = 0, nxt = 2;
    const int NK = FF/32;   // 112
    for (int t = 0; t < NK; ++t) {
        const ushort* Ab = &As[cur][0];
        const ushort* Bb = &Bs[cur][0];
        const bool pf = (t + 2 < NK);
        s16x8 a[4], b[4];
        #pragma unroll
        for (int n = 0; n < 4; ++n) b[n] = *(const s16x8*)(Bb + n*512 + rdB);
        #pragma unroll
        for (int m = 0; m < 4; ++m) a[m] = *(const s16x8*)(Ab + m*512 + rdA);
        if (pf) {
            gl_lds16(aS + (t+2)*32, &As[nxt][0] + wid*512);
            gl_lds16(bS + (t+2)*32,                &Bs[nxt][0] + wid*512);
            gl_lds16(bS + (size_t)(128*FF) + (t+2)*32, &Bs[nxt][0] + 4096 + wid*512);
        }
        BAR();
        LGKM0;
        __builtin_amdgcn_s_setprio(1);
        #pragma unroll
        for (int m = 0; m < 4; ++m)
            #pragma unroll
            for (int n = 0; n < 4; ++n)
                acc[m][n] = __builtin_amdgcn_mfma_f32_16x16x32_bf16(a[m], b[n], acc[m][n], 0, 0, 0);
        __builtin_amdgcn_s_setprio(0);
        if (t == NK-2) { VMC(0); } else { VMC(3); }
        BAR();
        cur = (cur == 2) ? 0 : cur + 1;
        nxt = (nxt == 2) ? 0 : nxt + 1;
    }

    #pragma unroll
    for (int m = 0; m < 4; ++m)
        #pragma unroll
        for (int j = 0; j < 4; ++j) {
            int prow = rowStart + wr*64 + m*16 + hi*4 + j;
            #pragma unroll
            for (int n = 0; n < 4; ++n) {
                int d = dc + wc*64 + n*16 + lo;
                res[(size_t)prow*DIM + d] = f2b(acc[m][n][j]);
            }
        }
}

__global__ __launch_bounds__(256)
void k_combine(const ushort* __restrict__ res, const int* __restrict__ tokPos,
               const float* __restrict__ topw, float* __restrict__ out)
{
    int i = blockIdx.x*256 + threadIdx.x;
    int t = i >> 7;
    int g = i & 127;
    int pA = tokPos[2*t], pB = tokPos[2*t+1];
    float wA = topw[2*t], wB = topw[2*t+1];
    uint4 a = *(const uint4*)(res + (size_t)pA*DIM + g*8);
    uint4 b = *(const uint4*)(res + (size_t)pB*DIM + g*8);
    float4 o0, o1;
    o0.x = wA*blo(a.x) + wB*blo(b.x);  o0.y = wA*bhi(a.x) + wB*bhi(b.x);
    o0.z = wA*blo(a.y) + wB*blo(b.y);  o0.w = wA*bhi(a.y) + wB*bhi(b.y);
    o1.x = wA*blo(a.z) + wB*blo(b.z);  o1.y = wA*bhi(a.z) + wB*bhi(b.z);
    o1.z = wA*blo(a.w) + wB*blo(b.w);  o1.w = wA*bhi(a.w) + wB*bhi(b.w);
    float4* dst = (float4*)(out + (size_t)t*DIM + g*8);
    dst[0] = o0; dst[1] = o1;
}

extern "C" void kernel_launch(void* const* d_in, const int* in_sizes, int n_in,
                              void* d_out, int out_size, void* d_ws, size_t ws_size,
                              hipStream_t stream)
{
    const float* x  = (const float*)d_in[0];
    const float* gw = (const float*)d_in[1];
    const float* w1 = (const float*)d_in[2];
    const float* w3 = (const float*)d_in[3];
    const float* w2 = (const float*)d_in[4];
    float* out = (float*)d_out;
    char* ws = (char*)d_ws;
    if (ws_size < WS_NEED) return;

    int*    counts = (int*)ws;
    int*    cursor = counts + 8;
    int*    offs   = counts + 16;
    int*    topi   = (int*)  (ws + OFF_TOPI);
    float*  topw   = (float*)(ws + OFF_TOPW);
    int*    tokPos = (int*)  (ws + OFF_TOKPOS);
    int*    rowTok = (int*)  (ws + OFF_ROWTOK);
    ushort* xb     = (ushort*)(ws + OFF_XB);
    ushort* w13b   = (ushort*)(ws + OFF_BIG);
    ushort* w2b    = (ushort*)(ws + OFF_W2B);
    ushort* res    = (ushort*)(ws + OFF_RES);
    ushort* h      = (ushort*)(ws + OFF_H);

    hipMemsetAsync(ws, 0, 256, stream);

    k_route  <<<T_TOK/4, 256, 0, stream>>>(x, gw, topi, topw, counts);
    k_scan   <<<1, 256, 0, stream>>>(counts, offs, rowTok);
    k_scatter<<<T_TOK/256, 256, 0, stream>>>(topi, offs, cursor, rowTok, tokPos);
    k_cvt    <<<(T_TOK*DIM/8)/256, 256, 0, stream>>>(x, xb);
    k_cvt13  <<<(2*NE*FF*DIM/8)/256, 256, 0, stream>>>(w1, w3, w13b);
    k_gemm1  <<<dim3(14, CAP/BM), 512, 0, stream>>>(xb, w13b, offs, rowTok, h);
    k_cvt    <<<(NE*DIM*FF/8)/256, 256, 0, stream>>>(w2, w2b);
    k_gemm2  <<<dim3(DIM/256, CAP/BM), 512, 0, stream>>>(h, w2b, offs, res);
    k_combine<<<(T_TOK*DIM/8)/256, 256, 0, stream>>>(res, tokPos, topw, out);
}

// Round 4
// 514.321 us; speedup vs baseline: 1.3534x; 1.0490x over previous
//
#include <hip/hip_runtime.h>
#include <hip/hip_bf16.h>

// Mixtral sparse MoE: T=4096 tokens, D=1024, F=3584, E=8, top-2.
// route -> scan(pad256) -> scatter -> cvt(x->xb in d_out) -> cvt13
//   -> GEMM1 (256x128 tile, ring-3, vmcnt(6), silu*mul -> h bf16)
//   -> cvt(w2) -> memset(out) -> GEMM2 (128x128, ring-3, vmcnt(4), atomic out)

#define T_TOK 4096
#define DIM   1024
#define FF    3584
#define NE    8
#define CAP   (T_TOK*2 + NE*256)   // 10240 padded pair rows (pad-256)

// ws byte offsets (WS_NEED = 190,988,544 <= verified 192,024,832)
#define OFF_TOPI   256UL
#define OFF_TOPW   33024UL
#define OFF_ROWTOK 65792UL
#define OFF_ROWW   106752UL
#define OFF_W13    147712UL
#define OFF_W2B    OFF_W13                      // overlays dead w13b after GEMM1
#define OFF_H      (OFF_W13 + 117440512UL)
#define WS_NEED    (OFF_H + 73400320UL)

using f32x4 = __attribute__((ext_vector_type(4))) float;
using s16x8 = __attribute__((ext_vector_type(8))) short;

__device__ __forceinline__ ushort f2b(float f) {
    __hip_bfloat16 b = __float2bfloat16(f);   // RNE
    ushort u; __builtin_memcpy(&u, &b, 2); return u;
}
__device__ __forceinline__ void gl_lds16(const ushort* g, ushort* l) {
    __builtin_amdgcn_global_load_lds(
        (const __attribute__((address_space(1))) void*)g,
        (__attribute__((address_space(3))) void*)l, 16, 0, 0);
}
__device__ __forceinline__ uint4 pack8(float4 v0, float4 v1) {
    uint4 o;
    o.x = f2b(v0.x) | ((uint)f2b(v0.y) << 16);
    o.y = f2b(v0.z) | ((uint)f2b(v0.w) << 16);
    o.z = f2b(v1.x) | ((uint)f2b(v1.y) << 16);
    o.w = f2b(v1.z) | ((uint)f2b(v1.w) << 16);
    return o;
}

#define LGKM0 do { asm volatile("s_waitcnt lgkmcnt(0)" ::: "memory"); \
                   __builtin_amdgcn_sched_barrier(0); } while (0)
#define VMC(n) asm volatile("s_waitcnt vmcnt(" #n ")" ::: "memory")
#define BAR()  __builtin_amdgcn_s_barrier()

// ---------------- routing: one wave per token ----------------
__global__ __launch_bounds__(256)
void k_route(const float* __restrict__ x, const float* __restrict__ gw,
             int* __restrict__ topi, float* __restrict__ topw, int* __restrict__ counts)
{
    __shared__ float gws[NE*DIM];
    const int tid = threadIdx.x;
    for (int i = tid; i < NE*DIM/4; i += 256)
        ((float4*)gws)[i] = ((const float4*)gw)[i];
    __syncthreads();

    const int lane = tid & 63, wid = tid >> 6;
    const int t = blockIdx.x*4 + wid;

    float4 xr[4];
    const float4* xrow = (const float4*)(x + (size_t)t*DIM) + lane*4;
    #pragma unroll
    for (int i = 0; i < 4; ++i) xr[i] = xrow[i];

    float lg[NE];
    #pragma unroll
    for (int e = 0; e < NE; ++e) {
        const float4* g4 = (const float4*)(gws + e*DIM) + lane*4;
        float s = 0.f;
        #pragma unroll
        for (int i = 0; i < 4; ++i) {
            float4 g = g4[i];
            s += xr[i].x*g.x + xr[i].y*g.y + xr[i].z*g.z + xr[i].w*g.w;
        }
        #pragma unroll
        for (int off = 32; off; off >>= 1) s += __shfl_xor(s, off);
        lg[e] = s;
    }
    if (lane == 0) {
        float b1 = -1e30f, b2 = -1e30f; int i1 = 0, i2 = 0;
        #pragma unroll
        for (int e = 0; e < NE; ++e) {
            float v = lg[e];
            if (v > b1)      { b2 = b1; i2 = i1; b1 = v; i1 = e; }
            else if (v > b2) { b2 = v; i2 = e; }
        }
        float p2 = __expf(b2 - b1);     // softmax denom cancels in top-k renorm
        float inv = 1.f / (1.f + p2);
        topi[2*t]   = i1; topi[2*t+1] = i2;
        topw[2*t]   = inv; topw[2*t+1] = p2*inv;
        atomicAdd(&counts[i1], 1); atomicAdd(&counts[i2], 1);
    }
}

// ---------------- scan: per-expert offsets padded to 256 ----------------
__global__ void k_scan(const int* __restrict__ counts, int* __restrict__ offs,
                       int* __restrict__ rowTok)
{
    if (threadIdx.x == 0) {
        int acc = 0; offs[0] = 0;
        for (int e = 0; e < NE; ++e) {
            int p = (counts[e] + 255) & ~255;
            acc += p; offs[e+1] = acc;
        }
    }
    for (int i = threadIdx.x; i < CAP; i += blockDim.x) rowTok[i] = -1;
}

// ---------------- scatter tokens into per-expert row lists ----------------
__global__ __launch_bounds__(256)
void k_scatter(const int* __restrict__ topi, const float* __restrict__ topw,
               const int* __restrict__ offs, int* __restrict__ cursor,
               int* __restrict__ rowTok, float* __restrict__ rowW)
{
    int t = blockIdx.x*256 + threadIdx.x;
    #pragma unroll
    for (int j = 0; j < 2; ++j) {
        int e = topi[2*t + j];
        int pos = offs[e] + atomicAdd(&cursor[e], 1);
        rowTok[pos] = t;
        rowW[pos] = topw[2*t + j];
    }
}

// ---------------- fp32 -> bf16 straight ----------------
__global__ __launch_bounds__(256)
void k_cvt(const float* __restrict__ src, ushort* __restrict__ dst)
{
    size_t i = (size_t)blockIdx.x*256 + threadIdx.x;
    float4 v0 = ((const float4*)src)[2*i], v1 = ((const float4*)src)[2*i+1];
    ((uint4*)dst)[i] = pack8(v0, v1);
}

// w13 layout [e][sb 56][rd 128][k 1024]:
//   rd: g=rd>>5, s=(rd>>4)&1, idx=rd&15 ; f = sb*64 + g*16 + idx ; src = s? w3 : w1
__global__ __launch_bounds__(256)
void k_cvt13(const float* __restrict__ w1, const float* __restrict__ w3,
             ushort* __restrict__ w13)
{
    int i = blockIdx.x*256 + threadIdx.x;    // 8-elem group along k
    int k8 = i & 127;
    int r  = i >> 7;                          // 0..57343
    int rd = r & 127;
    int sb = (r >> 7) % 56;
    int e  = r / 7168;
    int f  = sb*64 + (rd >> 5)*16 + (rd & 15);
    const float* src = (((rd >> 4) & 1) ? w3 : w1) + ((size_t)e*FF + f)*DIM + k8*8;
    float4 v0 = ((const float4*)src)[0], v1 = ((const float4*)src)[1];
    ((uint4*)w13)[i] = pack8(v0, v1);
}

// ---------------- GEMM1: 256 rows x 128 stacked-cols, BK=32 ----------------
// 4 waves of 128x64, ring-3 LDS (72 KB, 2 blocks/CU), counted vmcnt(6).
#define G1_SLOT 12288   // ushorts per slot: A 8192 + B 4096
__global__ __launch_bounds__(256, 2)
void k_gemm1(const ushort* __restrict__ xb, const ushort* __restrict__ w13,
             const int* __restrict__ offs, const int* __restrict__ rowTok,
             ushort* __restrict__ hout)
{
    __shared__ __align__(16) ushort L[3*G1_SLOT];   // 72 KB
    const int rowStart = blockIdx.y * 256;
    if (rowStart >= offs[8]) return;
    int e = 0;
    #pragma unroll
    for (int k = 1; k < NE; ++k) if (rowStart >= offs[k]) e = k;
    const int sb = blockIdx.x;   // 0..55
    const ushort* __restrict__ Wb = w13 + (((size_t)e*56 + sb) * 128) * DIM;

    const int tid = threadIdx.x, lane = tid & 63, wid = tid >> 6;
    const int wr = wid >> 1, wc = wid & 1;     // wave tile 128x64
    const int lo = lane & 15, hi = lane >> 4;

    // staging: issue (j): row = j*64 + wid*16 + (lane>>2), chunk (lane&3)^((lane>>3)&3)
    const int srow = lane >> 2;
    const int sch  = (lane & 3) ^ ((lane >> 3) & 3);
    const ushort* aS[4];
    #pragma unroll
    for (int j = 0; j < 4; ++j) {
        int tk = rowTok[rowStart + j*64 + wid*16 + srow]; if (tk < 0) tk = 0;
        aS[j] = xb + (size_t)tk*DIM + sch*8;
    }
    const ushort* bS[2];
    #pragma unroll
    for (int j = 0; j < 2; ++j)
        bS[j] = Wb + (size_t)(j*64 + wid*16 + srow)*DIM + sch*8;
    ushort* const dA = L + wid*512;            // + slot*G1_SLOT + j*2048
    ushort* const dB = L + 8192 + wid*512;     // + slot*G1_SLOT + j*2048

    // read offsets (elements); swizzle sig = (lo>>1)&3
    const int sig = (lo >> 1) & 3;
    const int roff = ((hi ^ sig) * 8);
    int rdA[8], rdB[4];
    #pragma unroll
    for (int m = 0; m < 8; ++m) rdA[m] = (wr*128 + m*16 + lo)*32 + roff;
    #pragma unroll
    for (int n = 0; n < 4; ++n) rdB[n] = 8192 + (wc*64 + n*16 + lo)*32 + roff;

    f32x4 acc[8][4];
    #pragma unroll
    for (int m = 0; m < 8; ++m)
        #pragma unroll
        for (int n = 0; n < 4; ++n) acc[m][n] = (f32x4)(0.f);

    // prologue: stage K0 -> slot0, K1 -> slot1 (6 issues each, FIFO order A0-3,B0-1)
    #pragma unroll
    for (int t0 = 0; t0 < 2; ++t0) {
        #pragma unroll
        for (int j = 0; j < 4; ++j) gl_lds16(aS[j] + t0*32, dA + t0*G1_SLOT + j*2048);
        #pragma unroll
        for (int j = 0; j < 2; ++j) gl_lds16(bS[j] + t0*32, dB + t0*G1_SLOT + j*2048);
    }
    VMC(6);
    BAR();

    const int NK = DIM/32;   // 32
    int cur = 0, nxt = 2;
    for (int t = 0; t < NK; ++t) {
        const ushort* Lb = L + cur*G1_SLOT;
        const bool pf = (t + 2 < NK);
        s16x8 a[4], b[4];
        // ---- phase 0: m 0..3 ----
        #pragma unroll
        for (int n = 0; n < 4; ++n) b[n] = *(const s16x8*)(Lb + rdB[n]);
        #pragma unroll
        for (int m = 0; m < 4; ++m) a[m] = *(const s16x8*)(Lb + rdA[m]);
        if (pf) {
            #pragma unroll
            for (int j = 0; j < 3; ++j)
                gl_lds16(aS[j] + (t+2)*32, dA + nxt*G1_SLOT + j*2048);
        }
        BAR();
        LGKM0;
        __builtin_amdgcn_s_setprio(1);
        #pragma unroll
        for (int m = 0; m < 4; ++m)
            #pragma unroll
            for (int n = 0; n < 4; ++n)
                acc[m][n] = __builtin_amdgcn_mfma_f32_16x16x32_bf16(a[m], b[n], acc[m][n], 0, 0, 0);
        __builtin_amdgcn_s_setprio(0);
        BAR();
        // ---- phase 1: m 4..7 ----
        #pragma unroll
        for (int m = 0; m < 4; ++m) a[m] = *(const s16x8*)(Lb + rdA[4+m]);
        if (pf) {
            gl_lds16(aS[3] + (t+2)*32, dA + nxt*G1_SLOT + 3*2048);
            gl_lds16(bS[0] + (t+2)*32, dB + nxt*G1_SLOT);
            gl_lds16(bS[1] + (t+2)*32, dB + nxt*G1_SLOT + 2048);
        }
        BAR();
        LGKM0;
        __builtin_amdgcn_s_setprio(1);
        #pragma unroll
        for (int m = 0; m < 4; ++m)
            #pragma unroll
            for (int n = 0; n < 4; ++n)
                acc[4+m][n] = __builtin_amdgcn_mfma_f32_16x16x32_bf16(a[m], b[n], acc[4+m][n], 0, 0, 0);
        __builtin_amdgcn_s_setprio(0);
        if (t < NK-2) { VMC(6); } else { VMC(0); }
        BAR();
        cur = (cur == 2) ? 0 : cur + 1;
        nxt = (nxt == 2) ? 0 : nxt + 1;
    }

    // epilogue: silu(w1)*w3 -> h ; pair = (acc[m][2p], acc[m][2p+1])
    #pragma unroll
    for (int m = 0; m < 8; ++m)
        #pragma unroll
        for (int p = 0; p < 2; ++p) {
            f32x4 v1 = acc[m][2*p], v3 = acc[m][2*p+1];
            int f = sb*64 + (wc*2 + p)*16 + lo;
            #pragma unroll
            for (int j = 0; j < 4; ++j) {
                int row = rowStart + wr*128 + m*16 + hi*4 + j;
                float s = v1[j];
                float val = (s / (1.f + __expf(-s))) * v3[j];
                hout[(size_t)row*FF + f] = f2b(val);
            }
        }
}

// ---------------- GEMM2: 128 rows x 128 d-cols, BK=32 ----------------
// 4 waves of 64x64, ring-3 LDS (48 KB, 3 blocks/CU), vmcnt(4), atomic epilogue.
#define G2_SLOT 8192   // ushorts per slot: A 4096 + B 4096
__global__ __launch_bounds__(256, 3)
void k_gemm2(const ushort* __restrict__ h, const ushort* __restrict__ w2b,
             const int* __restrict__ offs, const int* __restrict__ rowTok,
             const float* __restrict__ rowW, float* __restrict__ out)
{
    __shared__ __align__(16) ushort L[3*G2_SLOT];   // 48 KB
    const int rowStart = blockIdx.y * 128;
    if (rowStart >= offs[8]) return;
    int e = 0;
    #pragma unroll
    for (int k = 1; k < NE; ++k) if (rowStart >= offs[k]) e = k;
    const int dc = blockIdx.x * 128;
    const ushort* __restrict__ W2 = w2b + ((size_t)e*DIM + dc)*FF;

    const int tid = threadIdx.x, lane = tid & 63, wid = tid >> 6;
    const int wr = wid >> 1, wc = wid & 1;     // wave tile 64x64
    const int lo = lane & 15, hi = lane >> 4;

    const int srow = lane >> 2;
    const int sch  = (lane & 3) ^ ((lane >> 3) & 3);
    const ushort* aS[2];
    const ushort* bS[2];
    #pragma unroll
    for (int j = 0; j < 2; ++j) {
        int r = j*64 + wid*16 + srow;
        aS[j] = h  + (size_t)(rowStart + r)*FF + sch*8;
        bS[j] = W2 + (size_t)r*FF + sch*8;
    }
    ushort* const dA = L + wid*512;
    ushort* const dB = L + 4096 + wid*512;

    const int sig = (lo >> 1) & 3;
    const int roff = ((hi ^ sig) * 8);
    int rdA[4], rdB[4];
    #pragma unroll
    for (int m = 0; m < 4; ++m) rdA[m] = (wr*64 + m*16 + lo)*32 + roff;
    #pragma unroll
    for (int n = 0; n < 4; ++n) rdB[n] = 4096 + (wc*64 + n*16 + lo)*32 + roff;

    f32x4 acc[4][4];
    #pragma unroll
    for (int m = 0; m < 4; ++m)
        #pragma unroll
        for (int n = 0; n < 4; ++n) acc[m][n] = (f32x4)(0.f);

    #pragma unroll
    for (int t0 = 0; t0 < 2; ++t0) {
        #pragma unroll
        for (int j = 0; j < 2; ++j) gl_lds16(aS[j] + t0*32, dA + t0*G2_SLOT + j*2048);
        #pragma unroll
        for (int j = 0; j < 2; ++j) gl_lds16(bS[j] + t0*32, dB + t0*G2_SLOT + j*2048);
    }
    VMC(4);
    BAR();

    const int NK = FF/32;   // 112
    int cur = 0, nxt = 2;
    for (int t = 0; t < NK; ++t) {
        const ushort* Lb = L + cur*G2_SLOT;
        const bool pf = (t + 2 < NK);
        s16x8 a[4], b[4];
        #pragma unroll
        for (int n = 0; n < 4; ++n) b[n] = *(const s16x8*)(Lb + rdB[n]);
        #pragma unroll
        for (int m = 0; m < 4; ++m) a[m] = *(const s16x8*)(Lb + rdA[m]);
        if (pf) {
            #pragma unroll
            for (int j = 0; j < 2; ++j) gl_lds16(aS[j] + (t+2)*32, dA + nxt*G2_SLOT + j*2048);
            #pragma unroll
            for (int j = 0; j < 2; ++j) gl_lds16(bS[j] + (t+2)*32, dB + nxt*G2_SLOT + j*2048);
        }
        BAR();
        LGKM0;
        __builtin_amdgcn_s_setprio(1);
        #pragma unroll
        for (int m = 0; m < 4; ++m)
            #pragma unroll
            for (int n = 0; n < 4; ++n)
                acc[m][n] = __builtin_amdgcn_mfma_f32_16x16x32_bf16(a[m], b[n], acc[m][n], 0, 0, 0);
        __builtin_amdgcn_s_setprio(0);
        if (t < NK-2) { VMC(4); } else { VMC(0); }
        BAR();
        cur = (cur == 2) ? 0 : cur + 1;
        nxt = (nxt == 2) ? 0 : nxt + 1;
    }

    // epilogue: out[tok] += rw * acc  (2 atomics per output element total)
    #pragma unroll
    for (int m = 0; m < 4; ++m)
        #pragma unroll
        for (int j = 0; j < 4; ++j) {
            int prow = rowStart + wr*64 + m*16 + hi*4 + j;
            int tok = rowTok[prow];
            if (tok < 0) continue;
            float w = rowW[prow];
            #pragma unroll
            for (int n = 0; n < 4; ++n) {
                int d = dc + wc*64 + n*16 + lo;
                atomicAdd(&out[(size_t)tok*DIM + d], w * acc[m][n][j]);
            }
        }
}

// ---------------- launch ----------------
extern "C" void kernel_launch(void* const* d_in, const int* in_sizes, int n_in,
                              void* d_out, int out_size, void* d_ws, size_t ws_size,
                              hipStream_t stream)
{
    const float* x  = (const float*)d_in[0];
    const float* gw = (const float*)d_in[1];
    const float* w1 = (const float*)d_in[2];
    const float* w3 = (const float*)d_in[3];
    const float* w2 = (const float*)d_in[4];
    float* out = (float*)d_out;
    char* ws = (char*)d_ws;
    if (ws_size < WS_NEED) return;   // fail loudly

    int*    counts = (int*)ws;
    int*    cursor = counts + 8;
    int*    offs   = counts + 16;
    int*    topi   = (int*)  (ws + OFF_TOPI);
    float*  topw   = (float*)(ws + OFF_TOPW);
    int*    rowTok = (int*)  (ws + OFF_ROWTOK);
    float*  rowW   = (float*)(ws + OFF_ROWW);
    ushort* w13b   = (ushort*)(ws + OFF_W13);
    ushort* w2b    = (ushort*)(ws + OFF_W2B);
    ushort* h      = (ushort*)(ws + OFF_H);
    ushort* xb     = (ushort*)d_out;          // xb lives in d_out until post-GEMM1

    hipMemsetAsync(ws, 0, 256, stream);   // counts + cursor

    k_route  <<<T_TOK/4, 256, 0, stream>>>(x, gw, topi, topw, counts);
    k_scan   <<<1, 256, 0, stream>>>(counts, offs, rowTok);
    k_scatter<<<T_TOK/256, 256, 0, stream>>>(topi, topw, offs, cursor, rowTok, rowW);
    k_cvt    <<<(T_TOK*DIM/8)/256, 256, 0, stream>>>(x, xb);
    k_cvt13  <<<(2*NE*FF*DIM/8)/256, 256, 0, stream>>>(w1, w3, w13b);
    k_gemm1  <<<dim3(56, CAP/256), 256, 0, stream>>>(xb, w13b, offs, rowTok, h);
    k_cvt    <<<(NE*DIM*FF/8)/256, 256, 0, stream>>>(w2, w2b);   // overlays w13b
    hipMemsetAsync(d_out, 0, (size_t)T_TOK*DIM*4, stream);       // kills xb (dead)
    k_gemm2  <<<dim3(DIM/128, CAP/128), 256, 0, stream>>>(h, w2b, offs, rowTok, rowW, out);
}